// Round 4
// baseline (266.002 us; speedup 1.0000x reference)
//
#include <hip/hip_runtime.h>
#include <hip/hip_bf16.h>

// B=256, x:[B,80,14,14] f32, w1:[512,80], b1:[512], w2:[512,512], b2:[512],
// w3:[512,4,14,14], fc_w:[80,2048], fc_b:[80] -> out:[B,80] f32.
// h2 = (w2@w1) x + (w2@b1+b2); bias folded as k-channel 80 (x col 80 = 1.0).
#define CIN 80
#define NSP 196
#define HWP 208        // hw padded 196->208 (13 n-tiles of 16)
#define KP  96         // k padded 80(+bias)->96 (3 MFMA k-steps of 32)

#define NB_A 32        // Wc compose: block owns 16 o-rows, loops all 8 k-chunks
#define NB_B 1024      // x-prep: 4 hw-quarters per batch
#define NB_C 512       // w3 transpose
#define NB_D 64        // fc_w transpose (64*2560 = 163840 = 2048*80)
#define NB_E 16        // out init (16*1280 = 20480 = 256*80)

typedef __attribute__((ext_vector_type(8))) short  short8;
typedef __attribute__((ext_vector_type(4))) float  floatx4;

static __device__ __forceinline__ unsigned short bf16c(float f) {
    __hip_bfloat16 h = __float2bfloat16(f);
    return *(unsigned short*)&h;
}

// ---- kPre: ALL prep in one dispatch (no cross-block deps, no atomics) -------
__global__ __launch_bounds__(384) void kPre(
    const float* __restrict__ x,  const float* __restrict__ w1,
    const float* __restrict__ b1, const float* __restrict__ w2,
    const float* __restrict__ b2, const float* __restrict__ w3,
    const float* __restrict__ fc_w, const float* __restrict__ fc_b,
    unsigned short* __restrict__ Wcbf, unsigned short* __restrict__ xbf,
    float* __restrict__ w3t, float* __restrict__ fct, float* __restrict__ out)
{
    __shared__ float sm[6208];   // A: w1s[64*81]+w2s[16*64]=24832B; B: tile[80*53]
    const int blk = blockIdx.x, t = threadIdx.x;

    if (blk < NB_A) {
        // Wcbf[o][96] bf16 for o in [16*blk,16*blk+16); col 80 = bias, 81..95 = 0.
        const int ot = blk;
        float* w1s = sm;          // [64][81], col 80 = b1 chunk
        float* w2s = sm + 5184;   // [16][64]
        const int c = (t < 324) ? t % 81 : 0;
        const int oq = (t < 324) ? t / 81 : 0;     // o = ot*16 + oq + 4j
        float a0 = 0.f, a1 = 0.f, a2 = 0.f, a3 = 0.f;
        for (int kc = 0; kc < 8; ++kc) {
            for (int idx = t; idx < 64 * 81; idx += 384) {
                const int m = idx / 81, cc = idx - m * 81;
                w1s[idx] = (cc < CIN) ? w1[(kc * 64 + m) * CIN + cc] : b1[kc * 64 + m];
            }
            for (int idx = t; idx < 16 * 64; idx += 384) {
                const int o = idx >> 6, m = idx & 63;
                w2s[idx] = w2[(size_t)(ot * 16 + o) * 512 + kc * 64 + m];
            }
            __syncthreads();
            if (t < 324) {
                #pragma unroll 8
                for (int m = 0; m < 64; ++m) {
                    const float xv = w1s[m * 81 + c];
                    a0 = fmaf(w2s[(oq     ) * 64 + m], xv, a0);
                    a1 = fmaf(w2s[(oq +  4) * 64 + m], xv, a1);
                    a2 = fmaf(w2s[(oq +  8) * 64 + m], xv, a2);
                    a3 = fmaf(w2s[(oq + 12) * 64 + m], xv, a3);
                }
            }
            __syncthreads();
        }
        if (t < 324) {
            const float e = (c == CIN) ? 1.f : 0.f;   // add b2 on bias column
            Wcbf[(ot * 16 + oq     ) * KP + c] = bf16c(a0 + e * b2[ot * 16 + oq     ]);
            Wcbf[(ot * 16 + oq +  4) * KP + c] = bf16c(a1 + e * b2[ot * 16 + oq +  4]);
            Wcbf[(ot * 16 + oq +  8) * KP + c] = bf16c(a2 + e * b2[ot * 16 + oq +  8]);
            Wcbf[(ot * 16 + oq + 12) * KP + c] = bf16c(a3 + e * b2[ot * 16 + oq + 12]);
        }
        for (int idx = t; idx < 16 * 15; idx += 384) {   // zero cols 81..95
            const int r = idx / 15, cc = 81 + idx - r * 15;
            Wcbf[(ot * 16 + r) * KP + cc] = 0;
        }
    } else if (blk < NB_A + NB_B) {
        // x [b][80][196] f32 -> xbf [b][208][96] bf16 (col80=1, all pads=0)
        const int r = blk - NB_A;
        const int b = r >> 2, qt = r & 3, hw0 = qt * 52;
        float* tile = sm;   // [80][53]
        for (int idx = t; idx < 80 * 52; idx += 384) {
            const int k = idx / 52, hl = idx - k * 52;
            const int hw = hw0 + hl;
            tile[k * 53 + hl] = (hw < NSP) ? x[(size_t)b * CIN * NSP + k * NSP + hw] : 0.f;
        }
        __syncthreads();
        unsigned short* __restrict__ ob = xbf + (size_t)b * HWP * KP;
        for (int idx = t; idx < 52 * KP; idx += 384) {
            const int hl = idx / KP, k = idx - hl * KP;
            const int hw = hw0 + hl;
            float f = 0.f;
            if (hw < NSP) {
                if (k < CIN) f = tile[k * 53 + hl];
                else if (k == CIN) f = 1.f;          // bias channel
            }
            ob[(size_t)hw * KP + k] = bf16c(f);
        }
    } else if (blk < NB_A + NB_B + NB_C) {
        // w3 [g][4][196] -> w3t [g][208][4] f32, hw zero-padded
        const int g = blk - NB_A - NB_B;
        if (t < HWP) {
            floatx4 v;
            #pragma unroll
            for (int o = 0; o < 4; ++o)
                v[o] = (t < NSP) ? w3[(size_t)g * (4 * NSP) + o * NSP + t] : 0.f;
            *(floatx4*)(w3t + ((size_t)g * HWP + t) * 4) = v;
        }
    } else if (blk < NB_A + NB_B + NB_C + NB_D) {
        // fc_w [80][2048] -> fct [2048][80]
        const int rb = blk - NB_A - NB_B - NB_C;
        for (int idx = rb * 2560 + t; idx < rb * 2560 + 2560; idx += 384) {
            const int k = idx / CIN, l = idx - k * CIN;
            fct[idx] = fc_w[(size_t)l * 2048 + k];
        }
    } else {
        // out init = fc_b broadcast
        const int rb = blk - NB_A - NB_B - NB_C - NB_D;
        for (int idx = rb * 1280 + t; idx < rb * 1280 + 1280; idx += 384)
            out[idx] = fc_b[idx % CIN];
    }
}

// ---- kM: fused GEMM + conv3 + relu + fc-partial -----------------------------
// block = (bp: 4 batches, gc: 64 groups); 4 waves x 16 groups; 4b amortizes w3t.
__global__ __launch_bounds__(256, 3) void kM(
    const unsigned short* __restrict__ xbf, const unsigned short* __restrict__ Wcbf,
    const float* __restrict__ w3t, const float* __restrict__ fct,
    float* __restrict__ out)
{
    __shared__ float gl[4 * 256];   // [bi][k_local = glocal*4+o]
    const int bp = blockIdx.x, gc = blockIdx.y;
    const int w = threadIdx.x >> 6, lane = threadIdx.x & 63;
    const int col = lane & 15, quad = lane >> 4;
    const int g0 = gc * 64 + w * 16;       // wave's global group base
    const int b0 = bp * 4;

    // A-frags: 16 groups x 96 k, held in 12 VGPRs for the whole kernel
    const unsigned short* __restrict__ ap = Wcbf + (size_t)(g0 + col) * KP + quad * 8;
    short8 A[3];
    #pragma unroll
    for (int ks = 0; ks < 3; ++ks) A[ks] = *(const short8*)(ap + ks * 32);

    float p[4][4][4];   // conv3 partials [bi][r][o]
    #pragma unroll
    for (int bi = 0; bi < 4; ++bi)
        #pragma unroll
        for (int r = 0; r < 4; ++r)
            #pragma unroll
            for (int o = 0; o < 4; ++o) p[bi][r][o] = 0.f;

    const unsigned short* __restrict__ xb = xbf + (size_t)col * KP + quad * 8;
    const float* __restrict__ wb = w3t + ((size_t)(g0 + quad * 4) * HWP + col) * 4;

    #pragma unroll 2
    for (int nt = 0; nt < 13; ++nt) {
        floatx4 wv[4];   // w3t rows, shared by all 4 batches
        #pragma unroll
        for (int r = 0; r < 4; ++r)
            wv[r] = *(const floatx4*)(wb + ((size_t)r * HWP + nt * 16) * 4);
        #pragma unroll
        for (int bi = 0; bi < 4; ++bi) {
            const unsigned short* __restrict__ xp =
                xb + ((size_t)(b0 + bi) * HWP + nt * 16) * KP;
            const short8 x0 = *(const short8*)(xp);
            const short8 x1 = *(const short8*)(xp + 32);
            const short8 x2 = *(const short8*)(xp + 64);
            floatx4 acc = {0.f, 0.f, 0.f, 0.f};
            acc = __builtin_amdgcn_mfma_f32_16x16x32_bf16(A[0], x0, acc, 0, 0, 0);
            acc = __builtin_amdgcn_mfma_f32_16x16x32_bf16(A[1], x1, acc, 0, 0, 0);
            acc = __builtin_amdgcn_mfma_f32_16x16x32_bf16(A[2], x2, acc, 0, 0, 0);
            // C/D layout: col(hw)=lane&15, row(g)=quad*4+r  [m89-verified]
            #pragma unroll
            for (int r = 0; r < 4; ++r) {
                p[bi][r][0] = fmaf(acc[r], wv[r][0], p[bi][r][0]);
                p[bi][r][1] = fmaf(acc[r], wv[r][1], p[bi][r][1]);
                p[bi][r][2] = fmaf(acc[r], wv[r][2], p[bi][r][2]);
                p[bi][r][3] = fmaf(acc[r], wv[r][3], p[bi][r][3]);
            }
        }
    }

    // reduce over 16 hw-lanes, relu, stash in LDS
    #pragma unroll
    for (int bi = 0; bi < 4; ++bi)
        #pragma unroll
        for (int r = 0; r < 4; ++r) {
            float q0 = p[bi][r][0], q1 = p[bi][r][1], q2 = p[bi][r][2], q3 = p[bi][r][3];
            #pragma unroll
            for (int s = 8; s >= 1; s >>= 1) {
                q0 += __shfl_down(q0, s, 16);
                q1 += __shfl_down(q1, s, 16);
                q2 += __shfl_down(q2, s, 16);
                q3 += __shfl_down(q3, s, 16);
            }
            if (col == 0) {
                const int glocal = w * 16 + quad * 4 + r;
                floatx4 ov = {fmaxf(q0, 0.f), fmaxf(q1, 0.f), fmaxf(q2, 0.f), fmaxf(q3, 0.f)};
                *(floatx4*)(gl + bi * 256 + glocal * 4) = ov;
            }
        }
    __syncthreads();

    // fc partial over this block's 256 k-cols (k = gc*256 + klocal), 4 batches
    const int t = threadIdx.x;
    if (t < 160) {
        const int l = t % CIN, half = t / CIN;
        float s0 = 0.f, s1 = 0.f, s2 = 0.f, s3 = 0.f;
        const float* __restrict__ fr = fct + (size_t)(gc * 256 + half * 128) * CIN + l;
        const float* __restrict__ g0p = gl + half * 128;
        #pragma unroll 4
        for (int kk = 0; kk < 128; ++kk) {
            const float fv = fr[(size_t)kk * CIN];
            s0 = fmaf(g0p[kk      ], fv, s0);
            s1 = fmaf(g0p[kk + 256], fv, s1);
            s2 = fmaf(g0p[kk + 512], fv, s2);
            s3 = fmaf(g0p[kk + 768], fv, s3);
        }
        atomicAdd(out + (b0 + 0) * CIN + l, s0);
        atomicAdd(out + (b0 + 1) * CIN + l, s1);
        atomicAdd(out + (b0 + 2) * CIN + l, s2);
        atomicAdd(out + (b0 + 3) * CIN + l, s3);
    }
}

extern "C" void kernel_launch(void* const* d_in, const int* in_sizes, int n_in,
                              void* d_out, int out_size, void* d_ws, size_t ws_size,
                              hipStream_t stream) {
    const float* x    = (const float*)d_in[0];
    const float* w1   = (const float*)d_in[1];
    const float* b1   = (const float*)d_in[2];
    const float* w2   = (const float*)d_in[3];
    const float* b2   = (const float*)d_in[4];
    const float* w3   = (const float*)d_in[5];
    const float* fc_w = (const float*)d_in[6];
    const float* fc_b = (const float*)d_in[7];
    float* out = (float*)d_out;

    const int B = in_sizes[0] / (CIN * NSP);   // 256

    // workspace: xbf | Wcbf | w3t | fct   (~12.7 MB)
    char* ws = (char*)d_ws;
    unsigned short* xbf  = (unsigned short*)ws;                 // B*208*96*2
    size_t off = (size_t)B * HWP * KP * 2;
    unsigned short* Wcbf = (unsigned short*)(ws + off); off += 512 * KP * 2;
    float* w3t = (float*)(ws + off);  off += (size_t)512 * HWP * 4 * 4;
    float* fct = (float*)(ws + off);                            // 2048*80*4

    kPre<<<NB_A + NB_B + NB_C + NB_D + NB_E, 384, 0, stream>>>(
        x, w1, b1, w2, b2, w3, fc_w, fc_b, Wcbf, xbf, w3t, fct, out);
    kM<<<dim3(B / 4, 8), 256, 0, stream>>>(xbf, Wcbf, w3t, fct, out);
}